// Round 2
// baseline (54.045 us; speedup 1.0000x reference)
//
#include <hip/hip_runtime.h>
#include <hip/hip_cooperative_groups.h>

namespace cg = cooperative_groups;

// Problem constants (match reference file)
#define S_SAMPLES 1000
#define DIM 512   // floats per row = 128 float4s
#define NBLOCKS 250   // 250 blocks x 4 waves = 1000 waves, one per sample

// Fused single-node kernel:
//  Phase 1: one 64-lane wave per sample s. Lane l loads float4 #l and
//  #(l+64) of rows i,j,k (coalesced, 128 float4/row), accumulates the three
//  cross-dots and three self-dots, butterfly-reduces, lane 0 writes viol[s].
//  grid.sync()
//  Phase 2: block 0 deterministically tree-sums the 1000 violations -> mean.
__global__ __launch_bounds__(256) void trans_fused(
    const float* __restrict__ emb,
    const int* __restrict__ i_idx,
    const int* __restrict__ j_idx,
    const int* __restrict__ k_idx,
    float* __restrict__ viol,
    float* __restrict__ out)
{
    __shared__ float wsum[4];

    const int gtid = blockIdx.x * blockDim.x + threadIdx.x;
    const int s    = gtid >> 6;          // wave id = sample id (0..999 exactly)
    const int lane = threadIdx.x & 63;

    // ---- Phase 1: per-sample violation ----
    {
        const long long ri = (long long)i_idx[s] * DIM;
        const long long rj = (long long)j_idx[s] * DIM;
        const long long rk = (long long)k_idx[s] * DIM;
        const float4* pi = (const float4*)(emb + ri);
        const float4* pj = (const float4*)(emb + rj);
        const float4* pk = (const float4*)(emb + rk);

        float dij = 0.f, djk = 0.f, dik = 0.f;
        float nii = 0.f, njj = 0.f, nkk = 0.f;

#pragma unroll
        for (int t = 0; t < 2; ++t) {
            const int o = lane + 64 * t;   // 0..127 float4 index within row
            float4 a = pi[o];
            float4 b = pj[o];
            float4 c = pk[o];
            dij += a.x*b.x + a.y*b.y + a.z*b.z + a.w*b.w;
            djk += b.x*c.x + b.y*c.y + b.z*c.z + b.w*c.w;
            dik += a.x*c.x + a.y*c.y + a.z*c.z + a.w*c.w;
            nii += a.x*a.x + a.y*a.y + a.z*a.z + a.w*a.w;
            njj += b.x*b.x + b.y*b.y + b.z*b.z + b.w*b.w;
            nkk += c.x*c.x + c.y*c.y + c.z*c.z + c.w*c.w;
        }

        // 64-lane butterfly reduction (deterministic)
#pragma unroll
        for (int off = 32; off > 0; off >>= 1) {
            dij += __shfl_xor(dij, off);
            djk += __shfl_xor(djk, off);
            dik += __shfl_xor(dik, off);
            nii += __shfl_xor(nii, off);
            njj += __shfl_xor(njj, off);
            nkk += __shfl_xor(nkk, off);
        }

        if (lane == 0) {
            const float EPS = 1e-12f;
            const float ni = fmaxf(sqrtf(nii), EPS);
            const float nj = fmaxf(sqrtf(njj), EPS);
            const float nk = fmaxf(sqrtf(nkk), EPS);
            const float sij = dij / (ni * nj);
            const float sjk = djk / (nj * nk);
            const float sik = dik / (ni * nk);
            // TEMPERATURE == 1.0
            const float pij = 1.f / (1.f + expf(-sij));
            const float pjk = 1.f / (1.f + expf(-sjk));
            const float pik = 1.f / (1.f + expf(-sik));
            viol[s] = fmaxf(pij * pjk - pik, 0.f);
        }
    }

    __threadfence();
    cg::this_grid().sync();

    // ---- Phase 2: block 0 reduces 1000 violations -> mean ----
    if (blockIdx.x == 0) {
        const int t = threadIdx.x;
        float acc = 0.f;
        for (int idx = t; idx < S_SAMPLES; idx += 256) acc += viol[idx];
#pragma unroll
        for (int off = 32; off > 0; off >>= 1) acc += __shfl_xor(acc, off);
        if ((t & 63) == 0) wsum[t >> 6] = acc;
        __syncthreads();
        if (t == 0) {
            const float tot = wsum[0] + wsum[1] + wsum[2] + wsum[3];
            out[0] = tot * (1.0f / (float)S_SAMPLES);
        }
    }
}

extern "C" void kernel_launch(void* const* d_in, const int* in_sizes, int n_in,
                              void* d_out, int out_size, void* d_ws, size_t ws_size,
                              hipStream_t stream) {
    const float* emb  = (const float*)d_in[0];
    const int* i_idx  = (const int*)d_in[1];
    const int* j_idx  = (const int*)d_in[2];
    const int* k_idx  = (const int*)d_in[3];
    float* out  = (float*)d_out;
    float* viol = (float*)d_ws;   // S_SAMPLES floats of scratch

    void* args[] = { (void*)&emb, (void*)&i_idx, (void*)&j_idx, (void*)&k_idx,
                     (void*)&viol, (void*)&out };
    hipLaunchCooperativeKernel((void*)trans_fused, dim3(NBLOCKS), dim3(256),
                               args, 0, stream);
}

// Round 3
// 14.062 us; speedup vs baseline: 3.8434x; 3.8434x over previous
//
#include <hip/hip_runtime.h>

// Problem constants (match reference file)
#define S_SAMPLES 1000
#define DIM 512        // floats per row = 128 float4s
#define NBLOCKS 250    // 250 blocks x 4 waves = 1000 waves, one per sample

// Single-node fused kernel with last-block-done reduction.
//  Phase 1: one 64-lane wave per sample. Lane l loads float4 #l and #(l+64)
//  of rows i,j,k (coalesced), accumulates 3 cross-dots + 3 self-dots,
//  butterfly-reduces, lane 0 puts the violation in LDS.
//  Block epilogue: thread 0 sums its 4 wave violations (fixed order) into
//  part[blockIdx.x], device-fences, atomicAdd on a counter. The last
//  arriving block (old % NBLOCKS == NBLOCKS-1 — works for ANY poisoned
//  initial counter value, no init needed) acquires and reduces the 250
//  partials in a fixed lane-strided order -> deterministic mean.
__global__ __launch_bounds__(256) void trans_fused(
    const float* __restrict__ emb,
    const int* __restrict__ i_idx,
    const int* __restrict__ j_idx,
    const int* __restrict__ k_idx,
    float* __restrict__ part,          // NBLOCKS floats in d_ws
    unsigned int* __restrict__ counter, // 1 uint in d_ws (never initialized)
    float* __restrict__ out)
{
    __shared__ float vsh[4];
    __shared__ int last_flag;

    const int wave = threadIdx.x >> 6;             // 0..3
    const int lane = threadIdx.x & 63;
    const int s    = blockIdx.x * 4 + wave;        // sample id, 0..999 exactly

    // ---- Phase 1: per-sample violation ----
    {
        const long long ri = (long long)i_idx[s] * DIM;
        const long long rj = (long long)j_idx[s] * DIM;
        const long long rk = (long long)k_idx[s] * DIM;
        const float4* pi = (const float4*)(emb + ri);
        const float4* pj = (const float4*)(emb + rj);
        const float4* pk = (const float4*)(emb + rk);

        float dij = 0.f, djk = 0.f, dik = 0.f;
        float nii = 0.f, njj = 0.f, nkk = 0.f;

#pragma unroll
        for (int t = 0; t < 2; ++t) {
            const int o = lane + 64 * t;   // 0..127 float4 index within row
            float4 a = pi[o];
            float4 b = pj[o];
            float4 c = pk[o];
            dij += a.x*b.x + a.y*b.y + a.z*b.z + a.w*b.w;
            djk += b.x*c.x + b.y*c.y + b.z*c.z + b.w*c.w;
            dik += a.x*c.x + a.y*c.y + a.z*c.z + a.w*c.w;
            nii += a.x*a.x + a.y*a.y + a.z*a.z + a.w*a.w;
            njj += b.x*b.x + b.y*b.y + b.z*b.z + b.w*b.w;
            nkk += c.x*c.x + c.y*c.y + c.z*c.z + c.w*c.w;
        }

#pragma unroll
        for (int off = 32; off > 0; off >>= 1) {
            dij += __shfl_xor(dij, off);
            djk += __shfl_xor(djk, off);
            dik += __shfl_xor(dik, off);
            nii += __shfl_xor(nii, off);
            njj += __shfl_xor(njj, off);
            nkk += __shfl_xor(nkk, off);
        }

        if (lane == 0) {
            const float EPS = 1e-12f;
            const float ni = fmaxf(sqrtf(nii), EPS);
            const float nj = fmaxf(sqrtf(njj), EPS);
            const float nk = fmaxf(sqrtf(nkk), EPS);
            const float sij = dij / (ni * nj);
            const float sjk = djk / (nj * nk);
            const float sik = dik / (ni * nk);
            // TEMPERATURE == 1.0
            const float pij = 1.f / (1.f + expf(-sij));
            const float pjk = 1.f / (1.f + expf(-sjk));
            const float pik = 1.f / (1.f + expf(-sik));
            vsh[wave] = fmaxf(pij * pjk - pik, 0.f);
        }
    }

    __syncthreads();

    // ---- Block epilogue: write partial, signal, detect last block ----
    if (threadIdx.x == 0) {
        const float p = vsh[0] + vsh[1] + vsh[2] + vsh[3];  // fixed order
        part[blockIdx.x] = p;
        __threadfence();                                     // release
        const unsigned int old = atomicAdd(counter, 1u);
        last_flag = (old % (unsigned int)NBLOCKS == (unsigned int)(NBLOCKS - 1));
    }
    __syncthreads();

    // ---- Last arriving block: deterministic final reduction ----
    if (last_flag) {
        __threadfence();                                     // acquire
        if (threadIdx.x < 64) {
            float acc = 0.f;
            // lanes 0..63 each sum parts lane, lane+64, lane+128, lane+192
#pragma unroll
            for (int t = 0; t < 4; ++t) {
                const int idx = threadIdx.x + 64 * t;
                if (idx < NBLOCKS) acc += part[idx];
            }
#pragma unroll
            for (int off = 32; off > 0; off >>= 1) acc += __shfl_xor(acc, off);
            if (threadIdx.x == 0) out[0] = acc * (1.0f / (float)S_SAMPLES);
        }
    }
}

extern "C" void kernel_launch(void* const* d_in, const int* in_sizes, int n_in,
                              void* d_out, int out_size, void* d_ws, size_t ws_size,
                              hipStream_t stream) {
    const float* emb  = (const float*)d_in[0];
    const int* i_idx  = (const int*)d_in[1];
    const int* j_idx  = (const int*)d_in[2];
    const int* k_idx  = (const int*)d_in[3];
    float* out  = (float*)d_out;

    float* part = (float*)d_ws;                              // 250 floats
    unsigned int* counter = (unsigned int*)((char*)d_ws + 4096); // uninit OK

    trans_fused<<<NBLOCKS, 256, 0, stream>>>(emb, i_idx, j_idx, k_idx,
                                             part, counter, out);
}

// Round 4
// 11.086 us; speedup vs baseline: 4.8751x; 1.2685x over previous
//
#include <hip/hip_runtime.h>

// Problem constants (match reference file)
#define S_SAMPLES 1000
#define DIM 512        // floats per row = 128 float4s
#define NBLOCKS 250    // 250 blocks x 4 waves = 1000 waves, one per sample

// Single-node fused kernel, last-block-done reduction with CHEAP sync:
// all cross-block communication is agent-scope atomics (sc1 ops to the
// coherent point) -- no __threadfence, no L2 writeback/invalidate.
//
//  Phase 1: one 64-lane wave per sample (coalesced float4 row reads,
//           butterfly reduce, violation into LDS).
//  Epilogue: thread 0 sums the block's 4 violations (fixed order), publishes
//           it with a RELAXED agent atomic_exchange (single global_atomic_swap,
//           coherent point, no cache flush). The exchange's returned old value
//           is consumed by an asm barrier -> hardware has ack'd the swap
//           before the counter fetch_add issues. Last arriving block
//           (old % NBLOCKS == NBLOCKS-1, correct for ANY poisoned initial
//           counter) reads the 250 partials with RELAXED agent atomic loads
//           (sc1, bypass stale caches) and reduces in fixed order.
__global__ __launch_bounds__(256) void trans_fused(
    const float* __restrict__ emb,
    const int* __restrict__ i_idx,
    const int* __restrict__ j_idx,
    const int* __restrict__ k_idx,
    unsigned int* __restrict__ part,    // NBLOCKS u32 (float bits) in d_ws
    unsigned int* __restrict__ counter, // 1 uint in d_ws (never initialized)
    float* __restrict__ out)
{
    __shared__ float vsh[4];
    __shared__ int last_flag;

    const int wave = threadIdx.x >> 6;             // 0..3
    const int lane = threadIdx.x & 63;
    const int s    = blockIdx.x * 4 + wave;        // sample id, 0..999 exactly

    // ---- Phase 1: per-sample violation ----
    {
        const long long ri = (long long)i_idx[s] * DIM;
        const long long rj = (long long)j_idx[s] * DIM;
        const long long rk = (long long)k_idx[s] * DIM;
        const float4* pi = (const float4*)(emb + ri);
        const float4* pj = (const float4*)(emb + rj);
        const float4* pk = (const float4*)(emb + rk);

        float dij = 0.f, djk = 0.f, dik = 0.f;
        float nii = 0.f, njj = 0.f, nkk = 0.f;

#pragma unroll
        for (int t = 0; t < 2; ++t) {
            const int o = lane + 64 * t;   // 0..127 float4 index within row
            float4 a = pi[o];
            float4 b = pj[o];
            float4 c = pk[o];
            dij += a.x*b.x + a.y*b.y + a.z*b.z + a.w*b.w;
            djk += b.x*c.x + b.y*c.y + b.z*c.z + b.w*c.w;
            dik += a.x*c.x + a.y*c.y + a.z*c.z + a.w*c.w;
            nii += a.x*a.x + a.y*a.y + a.z*a.z + a.w*a.w;
            njj += b.x*b.x + b.y*b.y + b.z*b.z + b.w*b.w;
            nkk += c.x*c.x + c.y*c.y + c.z*c.z + c.w*c.w;
        }

#pragma unroll
        for (int off = 32; off > 0; off >>= 1) {
            dij += __shfl_xor(dij, off);
            djk += __shfl_xor(djk, off);
            dik += __shfl_xor(dik, off);
            nii += __shfl_xor(nii, off);
            njj += __shfl_xor(njj, off);
            nkk += __shfl_xor(nkk, off);
        }

        if (lane == 0) {
            const float EPS = 1e-12f;
            const float ni = fmaxf(sqrtf(nii), EPS);
            const float nj = fmaxf(sqrtf(njj), EPS);
            const float nk = fmaxf(sqrtf(nkk), EPS);
            const float sij = dij / (ni * nj);
            const float sjk = djk / (nj * nk);
            const float sik = dik / (ni * nk);
            // TEMPERATURE == 1.0
            const float pij = 1.f / (1.f + expf(-sij));
            const float pjk = 1.f / (1.f + expf(-sjk));
            const float pik = 1.f / (1.f + expf(-sik));
            vsh[wave] = fmaxf(pij * pjk - pik, 0.f);
        }
    }

    __syncthreads();

    // ---- Epilogue: publish partial via atomic swap, bump counter ----
    if (threadIdx.x == 0) {
        const float p = vsh[0] + vsh[1] + vsh[2] + vsh[3];  // fixed order
        const unsigned int bits = __float_as_uint(p);
        // sc1 swap to coherent point; no cache writeback needed.
        const unsigned int old_bits = __hip_atomic_exchange(
            &part[blockIdx.x], bits, __ATOMIC_RELAXED, __HIP_MEMORY_SCOPE_AGENT);
        // Consume the ack: forces s_waitcnt on the swap's response and stops
        // the compiler from hoisting the counter add above it.
        asm volatile("" :: "v"(old_bits) : "memory");
        const unsigned int c = __hip_atomic_fetch_add(
            counter, 1u, __ATOMIC_RELAXED, __HIP_MEMORY_SCOPE_AGENT);
        last_flag = ((c % (unsigned int)NBLOCKS) == (unsigned int)(NBLOCKS - 1));
    }
    __syncthreads();

    // ---- Last arriving block: deterministic final reduction ----
    if (last_flag) {
        if (threadIdx.x < 64) {
            float acc = 0.f;
#pragma unroll
            for (int t = 0; t < 4; ++t) {
                const int idx = threadIdx.x + 64 * t;
                if (idx < NBLOCKS) {
                    const unsigned int b = __hip_atomic_load(
                        &part[idx], __ATOMIC_RELAXED, __HIP_MEMORY_SCOPE_AGENT);
                    acc += __uint_as_float(b);
                }
            }
#pragma unroll
            for (int off = 32; off > 0; off >>= 1) acc += __shfl_xor(acc, off);
            if (threadIdx.x == 0) out[0] = acc * (1.0f / (float)S_SAMPLES);
        }
    }
}

extern "C" void kernel_launch(void* const* d_in, const int* in_sizes, int n_in,
                              void* d_out, int out_size, void* d_ws, size_t ws_size,
                              hipStream_t stream) {
    const float* emb  = (const float*)d_in[0];
    const int* i_idx  = (const int*)d_in[1];
    const int* j_idx  = (const int*)d_in[2];
    const int* k_idx  = (const int*)d_in[3];
    float* out  = (float*)d_out;

    unsigned int* part    = (unsigned int*)d_ws;                 // 250 u32
    unsigned int* counter = (unsigned int*)((char*)d_ws + 4096); // uninit OK

    trans_fused<<<NBLOCKS, 256, 0, stream>>>(emb, i_idx, j_idx, k_idx,
                                             part, counter, out);
}

// Round 5
// 10.575 us; speedup vs baseline: 5.1105x; 1.0483x over previous
//
#include <hip/hip_runtime.h>

// Problem constants (match reference file)
#define S_SAMPLES 1000
#define DIM 512        // floats per row = 128 float4s
#define NBLOCKS 125    // 125 blocks x 8 waves = 1000 waves, one per sample
#define NTHREADS 512

// Single-node fused kernel, last-block-done reduction, agent-scope atomics
// only (no __threadfence / L2 writeback).
//  Phase 1: one 64-lane wave per sample (coalesced float4 row reads,
//           butterfly reduce, violation into LDS).
//  Epilogue: thread 0 sums the block's 8 violations (fixed order), publishes
//           with a relaxed agent atomic_exchange; the swap's returned value
//           is consumed (asm) so the hardware ack orders it before the
//           counter fetch_add. Last arriving block (old % NBLOCKS ==
//           NBLOCKS-1 -- correct for ANY poisoned initial counter value)
//           reads the 125 partials with relaxed agent atomic loads and
//           reduces in fixed order -> bit-deterministic mean.
__global__ __launch_bounds__(NTHREADS) void trans_fused(
    const float* __restrict__ emb,
    const int* __restrict__ i_idx,
    const int* __restrict__ j_idx,
    const int* __restrict__ k_idx,
    unsigned int* __restrict__ part,    // NBLOCKS u32 (float bits) in d_ws
    unsigned int* __restrict__ counter, // 1 uint in d_ws (never initialized)
    float* __restrict__ out)
{
    __shared__ float vsh[8];
    __shared__ int last_flag;

    const int wave = threadIdx.x >> 6;             // 0..7
    const int lane = threadIdx.x & 63;
    const int s    = blockIdx.x * 8 + wave;        // sample id, 0..999 exactly

    // ---- Phase 1: per-sample violation ----
    {
        const long long ri = (long long)i_idx[s] * DIM;
        const long long rj = (long long)j_idx[s] * DIM;
        const long long rk = (long long)k_idx[s] * DIM;
        const float4* pi = (const float4*)(emb + ri);
        const float4* pj = (const float4*)(emb + rj);
        const float4* pk = (const float4*)(emb + rk);

        float dij = 0.f, djk = 0.f, dik = 0.f;
        float nii = 0.f, njj = 0.f, nkk = 0.f;

#pragma unroll
        for (int t = 0; t < 2; ++t) {
            const int o = lane + 64 * t;   // 0..127 float4 index within row
            float4 a = pi[o];
            float4 b = pj[o];
            float4 c = pk[o];
            dij += a.x*b.x + a.y*b.y + a.z*b.z + a.w*b.w;
            djk += b.x*c.x + b.y*c.y + b.z*c.z + b.w*c.w;
            dik += a.x*c.x + a.y*c.y + a.z*c.z + a.w*c.w;
            nii += a.x*a.x + a.y*a.y + a.z*a.z + a.w*a.w;
            njj += b.x*b.x + b.y*b.y + b.z*b.z + b.w*b.w;
            nkk += c.x*c.x + c.y*c.y + c.z*c.z + c.w*c.w;
        }

#pragma unroll
        for (int off = 32; off > 0; off >>= 1) {
            dij += __shfl_xor(dij, off);
            djk += __shfl_xor(djk, off);
            dik += __shfl_xor(dik, off);
            nii += __shfl_xor(nii, off);
            njj += __shfl_xor(njj, off);
            nkk += __shfl_xor(nkk, off);
        }

        if (lane == 0) {
            const float EPS = 1e-12f;
            const float ni = fmaxf(sqrtf(nii), EPS);
            const float nj = fmaxf(sqrtf(njj), EPS);
            const float nk = fmaxf(sqrtf(nkk), EPS);
            const float sij = dij / (ni * nj);
            const float sjk = djk / (nj * nk);
            const float sik = dik / (ni * nk);
            // TEMPERATURE == 1.0
            const float pij = 1.f / (1.f + expf(-sij));
            const float pjk = 1.f / (1.f + expf(-sjk));
            const float pik = 1.f / (1.f + expf(-sik));
            vsh[wave] = fmaxf(pij * pjk - pik, 0.f);
        }
    }

    __syncthreads();

    // ---- Epilogue: publish partial via atomic swap, bump counter ----
    if (threadIdx.x == 0) {
        float p = 0.f;
#pragma unroll
        for (int w = 0; w < 8; ++w) p += vsh[w];            // fixed order
        const unsigned int bits = __float_as_uint(p);
        const unsigned int old_bits = __hip_atomic_exchange(
            &part[blockIdx.x], bits, __ATOMIC_RELAXED, __HIP_MEMORY_SCOPE_AGENT);
        // Consume the ack: forces the waitcnt on the swap's response before
        // the counter add can issue.
        asm volatile("" :: "v"(old_bits) : "memory");
        const unsigned int c = __hip_atomic_fetch_add(
            counter, 1u, __ATOMIC_RELAXED, __HIP_MEMORY_SCOPE_AGENT);
        last_flag = ((c % (unsigned int)NBLOCKS) == (unsigned int)(NBLOCKS - 1));
    }
    __syncthreads();

    // ---- Last arriving block: deterministic final reduction ----
    if (last_flag) {
        if (threadIdx.x < 64) {
            float acc = 0.f;
#pragma unroll
            for (int t = 0; t < 2; ++t) {
                const int idx = threadIdx.x + 64 * t;
                if (idx < NBLOCKS) {
                    const unsigned int b = __hip_atomic_load(
                        &part[idx], __ATOMIC_RELAXED, __HIP_MEMORY_SCOPE_AGENT);
                    acc += __uint_as_float(b);
                }
            }
#pragma unroll
            for (int off = 32; off > 0; off >>= 1) acc += __shfl_xor(acc, off);
            if (threadIdx.x == 0) out[0] = acc * (1.0f / (float)S_SAMPLES);
        }
    }
}

extern "C" void kernel_launch(void* const* d_in, const int* in_sizes, int n_in,
                              void* d_out, int out_size, void* d_ws, size_t ws_size,
                              hipStream_t stream) {
    const float* emb  = (const float*)d_in[0];
    const int* i_idx  = (const int*)d_in[1];
    const int* j_idx  = (const int*)d_in[2];
    const int* k_idx  = (const int*)d_in[3];
    float* out  = (float*)d_out;

    unsigned int* part    = (unsigned int*)d_ws;                 // 125 u32
    unsigned int* counter = (unsigned int*)((char*)d_ws + 4096); // uninit OK

    trans_fused<<<NBLOCKS, NTHREADS, 0, stream>>>(emb, i_idx, j_idx, k_idx,
                                                  part, counter, out);
}

// Round 6
// 9.737 us; speedup vs baseline: 5.5502x; 1.0860x over previous
//
#include <hip/hip_runtime.h>

// Problem constants (match reference file)
#define S_SAMPLES 1000
#define DIM 512        // floats per row = 128 float4s
#define NBLOCKS 64     // 64 blocks x 16 waves = 1024 waves; 24 idle-guarded
#define NTHREADS 1024
#define WAVES_PER_BLOCK 16

// Single-node fused kernel, last-block-done reduction, agent-scope relaxed
// atomics only (no __threadfence / L2 writeback).
//  Phase 1: one 64-lane wave per sample (coalesced float4 row reads,
//           butterfly reduce, violation into LDS). Waves with s >= 1000
//           contribute 0.
//  Epilogue: thread 0 sums the block's 16 violations (fixed order),
//           publishes with relaxed agent atomic_exchange; the swap's return
//           value is consumed (asm) so the hardware ack orders it before the
//           counter fetch_add. Last arriving block ((c & 63) == 63 --
//           correct for ANY poisoned initial counter value) is detected by
//           thread 0, broadcast within wave 0 by __shfl; wave 0 alone loads
//           the 64 partials (one relaxed agent atomic load per lane),
//           butterfly-reduces in fixed order, lane 0 writes the mean.
//           Waves 1..15 retire right after the publish -- no second barrier.
__global__ __launch_bounds__(NTHREADS) void trans_fused(
    const float* __restrict__ emb,
    const int* __restrict__ i_idx,
    const int* __restrict__ j_idx,
    const int* __restrict__ k_idx,
    unsigned int* __restrict__ part,    // NBLOCKS u32 (float bits) in d_ws
    unsigned int* __restrict__ counter, // 1 uint in d_ws (never initialized)
    float* __restrict__ out)
{
    __shared__ float vsh[WAVES_PER_BLOCK];

    const int wave = threadIdx.x >> 6;                    // 0..15
    const int lane = threadIdx.x & 63;
    const int s    = blockIdx.x * WAVES_PER_BLOCK + wave; // sample id

    // ---- Phase 1: per-sample violation ----
    if (s < S_SAMPLES) {
        const long long ri = (long long)i_idx[s] * DIM;
        const long long rj = (long long)j_idx[s] * DIM;
        const long long rk = (long long)k_idx[s] * DIM;
        const float4* pi = (const float4*)(emb + ri);
        const float4* pj = (const float4*)(emb + rj);
        const float4* pk = (const float4*)(emb + rk);

        float dij = 0.f, djk = 0.f, dik = 0.f;
        float nii = 0.f, njj = 0.f, nkk = 0.f;

#pragma unroll
        for (int t = 0; t < 2; ++t) {
            const int o = lane + 64 * t;   // 0..127 float4 index within row
            float4 a = pi[o];
            float4 b = pj[o];
            float4 c = pk[o];
            dij += a.x*b.x + a.y*b.y + a.z*b.z + a.w*b.w;
            djk += b.x*c.x + b.y*c.y + b.z*c.z + b.w*c.w;
            dik += a.x*c.x + a.y*c.y + a.z*c.z + a.w*c.w;
            nii += a.x*a.x + a.y*a.y + a.z*a.z + a.w*a.w;
            njj += b.x*b.x + b.y*b.y + b.z*b.z + b.w*b.w;
            nkk += c.x*c.x + c.y*c.y + c.z*c.z + c.w*c.w;
        }

#pragma unroll
        for (int off = 32; off > 0; off >>= 1) {
            dij += __shfl_xor(dij, off);
            djk += __shfl_xor(djk, off);
            dik += __shfl_xor(dik, off);
            nii += __shfl_xor(nii, off);
            njj += __shfl_xor(njj, off);
            nkk += __shfl_xor(nkk, off);
        }

        if (lane == 0) {
            const float EPS = 1e-12f;
            const float ni = fmaxf(sqrtf(nii), EPS);
            const float nj = fmaxf(sqrtf(njj), EPS);
            const float nk = fmaxf(sqrtf(nkk), EPS);
            const float sij = dij / (ni * nj);
            const float sjk = djk / (nj * nk);
            const float sik = dik / (ni * nk);
            // TEMPERATURE == 1.0
            const float pij = 1.f / (1.f + expf(-sij));
            const float pjk = 1.f / (1.f + expf(-sjk));
            const float pik = 1.f / (1.f + expf(-sik));
            vsh[wave] = fmaxf(pij * pjk - pik, 0.f);
        }
    } else {
        if (lane == 0) vsh[wave] = 0.f;
    }

    __syncthreads();

    // ---- Epilogue: thread 0 publishes partial, bumps counter ----
    int last = 0;
    if (threadIdx.x == 0) {
        float p = 0.f;
#pragma unroll
        for (int w = 0; w < WAVES_PER_BLOCK; ++w) p += vsh[w]; // fixed order
        const unsigned int bits = __float_as_uint(p);
        const unsigned int old_bits = __hip_atomic_exchange(
            &part[blockIdx.x], bits, __ATOMIC_RELAXED, __HIP_MEMORY_SCOPE_AGENT);
        // Consume the ack: the swap's response must arrive before the
        // counter add issues -> partials are visible before counts.
        asm volatile("" :: "v"(old_bits) : "memory");
        const unsigned int c = __hip_atomic_fetch_add(
            counter, 1u, __ATOMIC_RELAXED, __HIP_MEMORY_SCOPE_AGENT);
        last = ((c & (unsigned int)(NBLOCKS - 1)) == (unsigned int)(NBLOCKS - 1));
    }

    // ---- Wave 0 of the last arriving block: final reduction ----
    if (threadIdx.x < 64) {
        last = __shfl(last, 0);      // broadcast thread 0's flag within wave 0
        if (last) {
            const unsigned int b = __hip_atomic_load(
                &part[lane], __ATOMIC_RELAXED, __HIP_MEMORY_SCOPE_AGENT);
            float acc = __uint_as_float(b);
#pragma unroll
            for (int off = 32; off > 0; off >>= 1) acc += __shfl_xor(acc, off);
            if (lane == 0) out[0] = acc * (1.0f / (float)S_SAMPLES);
        }
    }
}

extern "C" void kernel_launch(void* const* d_in, const int* in_sizes, int n_in,
                              void* d_out, int out_size, void* d_ws, size_t ws_size,
                              hipStream_t stream) {
    const float* emb  = (const float*)d_in[0];
    const int* i_idx  = (const int*)d_in[1];
    const int* j_idx  = (const int*)d_in[2];
    const int* k_idx  = (const int*)d_in[3];
    float* out  = (float*)d_out;

    unsigned int* part    = (unsigned int*)d_ws;                 // 64 u32
    unsigned int* counter = (unsigned int*)((char*)d_ws + 4096); // uninit OK

    trans_fused<<<NBLOCKS, NTHREADS, 0, stream>>>(emb, i_idx, j_idx, k_idx,
                                                  part, counter, out);
}